// Round 3
// baseline (6622.280 us; speedup 1.0000x reference)
//
#include <hip/hip_runtime.h>

#define BB 32
#define HH 64
#define WW 64
#define TT 100
#define CO 8
#define KS 6
#define LP 2

// One thread per (b,h,w) site; carries ut/st for all 8 couts across T.
// Conv emulates a BLAS/Eigen-style f32 reduction: sequential FMA over taps
// in kh-major (im2col) order, single accumulator. Scan is (u - s*th) + wx
// with separately-rounded ops (order-insensitive: s*th exact, one sub, one add).
__global__ __launch_bounds__(256, 4)
void sconv2d_spike_kernel(const float* __restrict__ x,
                          const float* __restrict__ wgt,
                          const float* __restrict__ thresh,
                          float* __restrict__ out)
{
    // weights in LDS, tap-major [tap][co]: broadcast reads, no conflicts
    __shared__ float wds[KS * KS][CO];

    const int tid = threadIdx.x;
    for (int i = tid; i < KS * KS * CO; i += 256) {
        const int co  = i / (KS * KS);
        const int tap = i % (KS * KS);
        wds[tap][co] = wgt[co * (KS * KS) + tap];
    }
    __syncthreads();

    const float th = thresh[0];

    const int blk = blockIdx.x;
    const int b   = blk >> 4;         // 16 tiles per batch image
    const int tb  = blk & 15;
    const int h   = ((tb >> 2) << 4) + (tid >> 4);
    const int w   = ((tb & 3) << 4) + (tid & 15);

    const float* __restrict__ xb = x + (size_t)b * HH * WW * TT;
    float* __restrict__ ob = out + (size_t)b * CO * HH * WW * TT
                                 + (size_t)h * WW * TT + (size_t)w * TT;

    float ut[CO];
    float st[CO];
#pragma unroll
    for (int c = 0; c < CO; ++c) { ut[c] = 0.0f; st[c] = 0.0f; }

    for (int t0 = 0; t0 < TT; t0 += 4) {
        float wx[CO][4];
#pragma unroll
        for (int c = 0; c < CO; ++c)
#pragma unroll
            for (int j = 0; j < 4; ++j) wx[c][j] = 0.0f;

#pragma unroll
        for (int kh = 0; kh < KS; ++kh) {
            const int hh = h - LP + kh;
            const bool hv = (unsigned)hh < (unsigned)HH;
#pragma unroll
            for (int kw = 0; kw < KS; ++kw) {
                const int ww = w - LP + kw;
                float4 xv = make_float4(0.f, 0.f, 0.f, 0.f);
                if (hv && (unsigned)ww < (unsigned)WW) {
                    xv = *(const float4*)(xb + ((size_t)hh * WW + ww) * TT + t0);
                }
                const int tap = kh * KS + kw;
#pragma unroll
                for (int c = 0; c < CO; ++c) {
                    const float wd = wds[tap][c];
                    // sequential fused-FMA chain (BLAS/Eigen gebp rounding)
                    wx[c][0] = __fmaf_rn(wd, xv.x, wx[c][0]);
                    wx[c][1] = __fmaf_rn(wd, xv.y, wx[c][1]);
                    wx[c][2] = __fmaf_rn(wd, xv.z, wx[c][2]);
                    wx[c][3] = __fmaf_rn(wd, xv.w, wx[c][3]);
                }
            }
        }

#pragma unroll
        for (int c = 0; c < CO; ++c) {
            float u = ut[c];
            float s = st[c];
            float4 sv;
            // u = (u - s*th) + wx  -- s*th exact (0 or 0.8f), one sub, one add
            u = __fadd_rn(__fsub_rn(u, __fmul_rn(s, th)), wx[c][0]);
            s = (u > 0.0f) ? 1.0f : 0.0f; sv.x = s;
            u = __fadd_rn(__fsub_rn(u, __fmul_rn(s, th)), wx[c][1]);
            s = (u > 0.0f) ? 1.0f : 0.0f; sv.y = s;
            u = __fadd_rn(__fsub_rn(u, __fmul_rn(s, th)), wx[c][2]);
            s = (u > 0.0f) ? 1.0f : 0.0f; sv.z = s;
            u = __fadd_rn(__fsub_rn(u, __fmul_rn(s, th)), wx[c][3]);
            s = (u > 0.0f) ? 1.0f : 0.0f; sv.w = s;
            ut[c] = u;
            st[c] = s;
            *(float4*)(ob + (size_t)c * HH * WW * TT + t0) = sv;
        }
    }
}

extern "C" void kernel_launch(void* const* d_in, const int* in_sizes, int n_in,
                              void* d_out, int out_size, void* d_ws, size_t ws_size,
                              hipStream_t stream) {
    const float* x      = (const float*)d_in[0];
    const float* wgt    = (const float*)d_in[1];
    const float* thresh = (const float*)d_in[2];
    float* out = (float*)d_out;

    dim3 grid(4 * 4 * BB);   // (W/16)*(H/16)*B = 512 blocks
    dim3 block(256);
    sconv2d_spike_kernel<<<grid, block, 0, stream>>>(x, wgt, thresh, out);
}

// Round 4
// 1487.817 us; speedup vs baseline: 4.4510x; 4.4510x over previous
//
#include <hip/hip_runtime.h>

#define HH 64
#define WW 64
#define TT 100
#define CO 8
#define KS 6
#define LP 2
#define TILE 16
#define HALO (TILE + KS - 1)       // 21
#define NSITE (HALO * HALO)        // 441
#define NGMAX 7                    // max t-groups (28 t / 4) per chunk

__device__ __forceinline__ float stepu(float u, float s, float th, float wx) {
    // u = (u - s*th) + wx  -- exact reference association, no contraction
    return __fadd_rn(__fsub_rn(u, __fmul_rn(s, th)), wx);
}

template<int TC>
__device__ __forceinline__ void process_chunk(
    const float* __restrict__ xb, float* __restrict__ outb,
    float4* xs, float (*wds)[CO], unsigned (*stage)[CO + 1],
    int tid, int r, int c, int h0, int w0, int t0, float th,
    float* ut, float* sprev)
{
    constexpr int NG = TC / 4;

    // ---- cooperative load of x halo tile, t in [t0, t0+TC), float4 along t ----
    // flat idx = s_halo*NG + tg -> consecutive lanes read contiguous 16B chunks
    for (int i = tid; i < NSITE * NG; i += 256) {
        const int s  = i / NG;
        const int tg = i - s * NG;
        const int hr = s / HALO;
        const int hc = s - hr * HALO;
        const int hh = h0 - LP + hr;
        const int ww = w0 - LP + hc;
        float4 v = make_float4(0.f, 0.f, 0.f, 0.f);
        if ((unsigned)hh < (unsigned)HH && (unsigned)ww < (unsigned)WW)
            v = *(const float4*)(xb + ((size_t)hh * WW + ww) * TT + t0 + tg * 4);
        xs[tg * NSITE + s] = v;
    }
    __syncthreads();

    // ---- conv (from LDS, shared across couts) + scan (bits in regs) ----
    unsigned sb[CO];
#pragma unroll
    for (int co = 0; co < CO; ++co) sb[co] = 0u;

    for (int tg = 0; tg < NG; ++tg) {
        float4 wx[CO];
#pragma unroll
        for (int co = 0; co < CO; ++co) wx[co] = make_float4(0.f, 0.f, 0.f, 0.f);
#pragma unroll
        for (int kh = 0; kh < KS; ++kh) {
#pragma unroll
            for (int kw = 0; kw < KS; ++kw) {
                const float4 xv = xs[tg * NSITE + (r + kh) * HALO + (c + kw)];
                const int tap = kh * KS + kw;
#pragma unroll
                for (int co = 0; co < CO; ++co) {
                    const float wd = wds[tap][co];
                    // sequential fused-FMA chain, kh-major order (matches np ref)
                    wx[co].x = __fmaf_rn(wd, xv.x, wx[co].x);
                    wx[co].y = __fmaf_rn(wd, xv.y, wx[co].y);
                    wx[co].z = __fmaf_rn(wd, xv.z, wx[co].z);
                    wx[co].w = __fmaf_rn(wd, xv.w, wx[co].w);
                }
            }
        }
#pragma unroll
        for (int co = 0; co < CO; ++co) {
            float u = ut[co], s = sprev[co];
            unsigned bits = 0u;
            u = stepu(u, s, th, wx[co].x); s = (u > 0.f) ? 1.f : 0.f; bits |= (u > 0.f) ? 1u : 0u;
            u = stepu(u, s, th, wx[co].y); s = (u > 0.f) ? 1.f : 0.f; bits |= (u > 0.f) ? 2u : 0u;
            u = stepu(u, s, th, wx[co].z); s = (u > 0.f) ? 1.f : 0.f; bits |= (u > 0.f) ? 4u : 0u;
            u = stepu(u, s, th, wx[co].w); s = (u > 0.f) ? 1.f : 0.f; bits |= (u > 0.f) ? 8u : 0u;
            ut[co] = u; sprev[co] = s;
            sb[co] |= bits << (tg * 4);
        }
    }
#pragma unroll
    for (int co = 0; co < CO; ++co) stage[tid][co] = sb[co];
    __syncthreads();

    // ---- flush: expand bits -> floats, lanes along t (coalesced segments) ----
    for (int i = tid; i < 256 * CO * TC; i += 256) {
        const int u  = i / TC;              // packed (co,r,c)
        const int tt = i - u * TC;
        const int cc = u & 15;
        const int rr = (u >> 4) & 15;
        const int co = u >> 8;
        const unsigned bits = stage[rr * 16 + cc][co];
        const float v = ((bits >> tt) & 1u) ? 1.0f : 0.0f;
        outb[(((size_t)co * HH + (h0 + rr)) * WW + (w0 + cc)) * TT + t0 + tt] = v;
    }
    // no sync needed: next chunk writes xs (disjoint from stage); stage is
    // rewritten only after the next chunk's first __syncthreads.
}

__global__ __launch_bounds__(256, 2)
void sconv2d_spike_kernel(const float* __restrict__ x,
                          const float* __restrict__ wgt,
                          const float* __restrict__ thresh,
                          float* __restrict__ out)
{
    __shared__ float4   xs[NGMAX * NSITE];        // 49.4 KB
    __shared__ float    wds[KS * KS][CO];         // 1.2 KB
    __shared__ unsigned stage[256][CO + 1];       // 9.2 KB (pad -> conflict-free)

    const int tid = threadIdx.x;
    for (int i = tid; i < KS * KS * CO; i += 256) {
        const int co  = i / (KS * KS);
        const int tap = i - co * (KS * KS);
        wds[tap][co] = wgt[co * (KS * KS) + tap];
    }
    const float th = thresh[0];

    const int blk = blockIdx.x;
    const int b   = blk >> 4;
    const int tb  = blk & 15;
    const int h0  = (tb >> 2) << 4;
    const int w0  = (tb & 3) << 4;
    const int r   = tid >> 4;
    const int c   = tid & 15;

    const float* xb   = x   + (size_t)b * (HH * WW * TT);
    float*       outb = out + (size_t)b * (CO * HH * WW * TT);

    float ut[CO], sprev[CO];
#pragma unroll
    for (int co = 0; co < CO; ++co) { ut[co] = 0.f; sprev[co] = 0.f; }

    process_chunk<28>(xb, outb, xs, wds, stage, tid, r, c, h0, w0,  0, th, ut, sprev);
    process_chunk<28>(xb, outb, xs, wds, stage, tid, r, c, h0, w0, 28, th, ut, sprev);
    process_chunk<28>(xb, outb, xs, wds, stage, tid, r, c, h0, w0, 56, th, ut, sprev);
    process_chunk<16>(xb, outb, xs, wds, stage, tid, r, c, h0, w0, 84, th, ut, sprev);
}

extern "C" void kernel_launch(void* const* d_in, const int* in_sizes, int n_in,
                              void* d_out, int out_size, void* d_ws, size_t ws_size,
                              hipStream_t stream) {
    const float* x      = (const float*)d_in[0];
    const float* wgt    = (const float*)d_in[1];
    const float* thresh = (const float*)d_in[2];
    float* out = (float*)d_out;

    dim3 grid(16 * 32);   // 16 tiles per image x B=32
    dim3 block(256);
    sconv2d_spike_kernel<<<grid, block, 0, stream>>>(x, wgt, thresh, out);
}

// Round 6
// 1290.797 us; speedup vs baseline: 5.1304x; 1.1526x over previous
//
#include <hip/hip_runtime.h>

#define HH 64
#define WW 64
#define TT 100
#define CO 8
#define KS 6
#define LP 2
#define HALO 21                    // 16 + 6 - 1
#define NSITE 441                  // 21*21
#define NGMAX 7

__device__ __forceinline__ float stepu(float u, float s, float th, float wx) {
    // u = (u - s*th) + wx  -- exact reference association, no contraction
    return __fadd_rn(__fsub_rn(u, __fmul_rn(s, th)), wx);
}

// Stage x[t0..t0+TC) halo into LDS, conv (kh-major sequential FMA, bit-exact
// vs np ref), scan; accumulate spike bits in REGISTERS ONLY (static indices).
template<int T0, int TC>
__device__ __forceinline__ void process_chunk(
    const float* __restrict__ xb,
    float4* __restrict__ xs, const float (*wds)[CO],
    int tid, int r, int c, int h0, int w0, float th,
    float* ut, float* sprev, unsigned* bw /* CO*4 words, static idx only */)
{
    constexpr int NG = TC / 4;

    for (int i = tid; i < NSITE * NG; i += 256) {
        const int s  = i / NG;
        const int tg = i - s * NG;
        const int hr = s / HALO;
        const int hc = s - hr * HALO;
        const int hh = h0 - LP + hr;
        const int ww = w0 - LP + hc;
        float4 v = make_float4(0.f, 0.f, 0.f, 0.f);
        if ((unsigned)hh < (unsigned)HH && (unsigned)ww < (unsigned)WW)
            v = *(const float4*)(xb + ((size_t)hh * WW + ww) * TT + T0 + tg * 4);
        xs[tg * NSITE + s] = v;
    }
    __syncthreads();

    unsigned cb[CO];
#pragma unroll
    for (int co = 0; co < CO; ++co) cb[co] = 0u;

    for (int tg = 0; tg < NG; ++tg) {          // not unrolled (R4-proven shape)
        float4 wx[CO];
#pragma unroll
        for (int co = 0; co < CO; ++co) wx[co] = make_float4(0.f, 0.f, 0.f, 0.f);
#pragma unroll
        for (int kh = 0; kh < KS; ++kh) {
#pragma unroll
            for (int kw = 0; kw < KS; ++kw) {
                const float4 xv = xs[tg * NSITE + (r + kh) * HALO + (c + kw)];
                const int tap = kh * KS + kw;
#pragma unroll
                for (int co = 0; co < CO; ++co) {
                    const float wd = wds[tap][co];
                    wx[co].x = __fmaf_rn(wd, xv.x, wx[co].x);
                    wx[co].y = __fmaf_rn(wd, xv.y, wx[co].y);
                    wx[co].z = __fmaf_rn(wd, xv.z, wx[co].z);
                    wx[co].w = __fmaf_rn(wd, xv.w, wx[co].w);
                }
            }
        }
        const int sh = tg * 4;
#pragma unroll
        for (int co = 0; co < CO; ++co) {
            float u = ut[co], s = sprev[co];
            unsigned m = 0u;
            u = stepu(u, s, th, wx[co].x); s = (u > 0.f) ? 1.f : 0.f; m |= (u > 0.f) ? 1u : 0u;
            u = stepu(u, s, th, wx[co].y); s = (u > 0.f) ? 1.f : 0.f; m |= (u > 0.f) ? 2u : 0u;
            u = stepu(u, s, th, wx[co].z); s = (u > 0.f) ? 1.f : 0.f; m |= (u > 0.f) ? 4u : 0u;
            u = stepu(u, s, th, wx[co].w); s = (u > 0.f) ? 1.f : 0.f; m |= (u > 0.f) ? 8u : 0u;
            ut[co] = u; sprev[co] = s;
            cb[co] |= m << sh;
        }
    }
    __syncthreads();   // compute done before next chunk overwrites xs

    // merge chunk bits into full-T words; word index & shift are compile-time
    constexpr int W0 = T0 / 32;
    constexpr int S  = T0 % 32;
#pragma unroll
    for (int co = 0; co < CO; ++co) {
        bw[co * 4 + W0] |= cb[co] << S;
        if constexpr (S + TC > 32)
            bw[co * 4 + W0 + 1] |= cb[co] >> ((32 - S) & 31);
    }
}

__global__ __launch_bounds__(256, 2)
void sconv2d_spike_kernel(const float* __restrict__ x,
                          const float* __restrict__ wgt,
                          const float* __restrict__ thresh,
                          float* __restrict__ out)
{
    __shared__ float4   xs[NGMAX * NSITE];    // 49.4 KB
    __shared__ float    wds[KS * KS][CO];     // 1.2 KB
    __shared__ unsigned stg[256][5];          // 5.1 KB (stride 5: conflict-free)

    const int tid = threadIdx.x;
    for (int i = tid; i < KS * KS * CO; i += 256) {
        const int co  = i / (KS * KS);
        const int tap = i - co * (KS * KS);
        wds[tap][co] = wgt[co * (KS * KS) + tap];
    }
    const float th = thresh[0];

    const int blk = blockIdx.x;
    const int b   = blk >> 4;                 // R4-proven mapping
    const int tb  = blk & 15;
    const int h0  = (tb >> 2) << 4;
    const int w0  = (tb & 3) << 4;
    const int r   = tid >> 4;
    const int c   = tid & 15;

    const float* xb   = x   + (size_t)b * (HH * WW * TT);
    float*       outb = out + (size_t)b * (CO * HH * WW * TT);

    float ut[CO], sprev[CO];
    unsigned bw[CO * 4];
#pragma unroll
    for (int co = 0; co < CO; ++co) { ut[co] = 0.f; sprev[co] = 0.f; }
#pragma unroll
    for (int i = 0; i < CO * 4; ++i) bw[i] = 0u;

    process_chunk< 0, 28>(xb, xs, wds, tid, r, c, h0, w0, th, ut, sprev, bw);
    process_chunk<28, 28>(xb, xs, wds, tid, r, c, h0, w0, th, ut, sprev, bw);
    process_chunk<56, 28>(xb, xs, wds, tid, r, c, h0, w0, th, ut, sprev, bw);
    process_chunk<84, 16>(xb, xs, wds, tid, r, c, h0, w0, th, ut, sprev, bw);

    // ---- flush: co fully unrolled (bw indices static -> stays in VGPRs) ----
#pragma unroll
    for (int co = 0; co < CO; ++co) {
        stg[tid][0] = bw[co * 4 + 0];
        stg[tid][1] = bw[co * 4 + 1];
        stg[tid][2] = bw[co * 4 + 2];
        stg[tid][3] = bw[co * 4 + 3];
        __syncthreads();
#pragma unroll
        for (int k = 0; k < 25; ++k) {
            const int idx = tid + k * 256;        // 0..6399
            const int u   = idx / 25;             // site 0..255
            const int tt  = (idx - u * 25) * 4;   // t0 of this float4 (4-aligned)
            const unsigned bs = stg[u][tt >> 5] >> (tt & 31);
            float4 v;
            v.x = (float)( bs        & 1u);
            v.y = (float)((bs >> 1)  & 1u);
            v.z = (float)((bs >> 2)  & 1u);
            v.w = (float)((bs >> 3)  & 1u);
            const int rr = u >> 4, cc = u & 15;
            *(float4*)(outb + (((size_t)co * HH + (h0 + rr)) * WW + (w0 + cc)) * TT + tt) = v;
        }
        __syncthreads();
    }
}

extern "C" void kernel_launch(void* const* d_in, const int* in_sizes, int n_in,
                              void* d_out, int out_size, void* d_ws, size_t ws_size,
                              hipStream_t stream) {
    const float* x      = (const float*)d_in[0];
    const float* wgt    = (const float*)d_in[1];
    const float* thresh = (const float*)d_in[2];
    float* out = (float*)d_out;

    dim3 grid(16 * 32);   // 16 tiles per image x B=32 images
    dim3 block(256);
    sconv2d_spike_kernel<<<grid, block, 0, stream>>>(x, wgt, thresh, out);
}

// Round 7
// 550.658 us; speedup vs baseline: 12.0261x; 2.3441x over previous
//
#include <hip/hip_runtime.h>

#define HH 64
#define WW 64
#define TT 100
#define CO 8
#define COB 4                      // couts per block (split across 2 blocks)
#define KS 6
#define LP 2
#define HALO 21                    // 16 + 6 - 1
#define NSITE 441                  // 21*21
#define NGMAX 7

__device__ __forceinline__ float stepu(float u, float s, float th, float wx) {
    // u = (u - s*th) + wx  -- exact reference association, no contraction
    return __fadd_rn(__fsub_rn(u, __fmul_rn(s, th)), wx);
}

// Stage x[t0..t0+TC) halo into LDS, conv (kh-major sequential FMA, bit-exact
// vs np ref), scan; accumulate spike bits in registers (static indices only).
template<int T0, int TC>
__device__ __forceinline__ void process_chunk(
    const float* __restrict__ xb,
    float4* __restrict__ xs, const float (*wds)[CO],
    int tid, int r, int c, int h0, int w0, int co0, float th,
    float* ut, float* sprev, unsigned* bw /* COB*4 words, static idx */)
{
    constexpr int NG = TC / 4;

    for (int i = tid; i < NSITE * NG; i += 256) {
        const int s  = i / NG;
        const int tg = i - s * NG;
        const int hr = s / HALO;
        const int hc = s - hr * HALO;
        const int hh = h0 - LP + hr;
        const int ww = w0 - LP + hc;
        float4 v = make_float4(0.f, 0.f, 0.f, 0.f);
        if ((unsigned)hh < (unsigned)HH && (unsigned)ww < (unsigned)WW)
            v = *(const float4*)(xb + ((size_t)hh * WW + ww) * TT + T0 + tg * 4);
        xs[tg * NSITE + s] = v;
    }
    __syncthreads();

    unsigned cb[COB];
#pragma unroll
    for (int j = 0; j < COB; ++j) cb[j] = 0u;

    for (int tg = 0; tg < NG; ++tg) {
        float4 wx[COB];
#pragma unroll
        for (int j = 0; j < COB; ++j) wx[j] = make_float4(0.f, 0.f, 0.f, 0.f);
#pragma unroll
        for (int kh = 0; kh < KS; ++kh) {
#pragma unroll
            for (int kw = 0; kw < KS; ++kw) {
                const float4 xv = xs[tg * NSITE + (r + kh) * HALO + (c + kw)];
                const int tap = kh * KS + kw;
#pragma unroll
                for (int j = 0; j < COB; ++j) {
                    const float wd = wds[tap][co0 + j];
                    wx[j].x = __fmaf_rn(wd, xv.x, wx[j].x);
                    wx[j].y = __fmaf_rn(wd, xv.y, wx[j].y);
                    wx[j].z = __fmaf_rn(wd, xv.z, wx[j].z);
                    wx[j].w = __fmaf_rn(wd, xv.w, wx[j].w);
                }
            }
        }
        const int sh = tg * 4;
#pragma unroll
        for (int j = 0; j < COB; ++j) {
            float u = ut[j], s = sprev[j];
            unsigned m = 0u;
            u = stepu(u, s, th, wx[j].x); s = (u > 0.f) ? 1.f : 0.f; m |= (u > 0.f) ? 1u : 0u;
            u = stepu(u, s, th, wx[j].y); s = (u > 0.f) ? 1.f : 0.f; m |= (u > 0.f) ? 2u : 0u;
            u = stepu(u, s, th, wx[j].z); s = (u > 0.f) ? 1.f : 0.f; m |= (u > 0.f) ? 4u : 0u;
            u = stepu(u, s, th, wx[j].w); s = (u > 0.f) ? 1.f : 0.f; m |= (u > 0.f) ? 8u : 0u;
            ut[j] = u; sprev[j] = s;
            cb[j] |= m << sh;
        }
    }
    __syncthreads();   // compute done before next chunk overwrites xs

    constexpr int W0 = T0 / 32;
    constexpr int S  = T0 % 32;
#pragma unroll
    for (int j = 0; j < COB; ++j) {
        bw[j * 4 + W0] |= cb[j] << S;
        if constexpr (S + TC > 32)
            bw[j * 4 + W0 + 1] |= cb[j] >> ((32 - S) & 31);
    }
}

__global__ __launch_bounds__(256, 2)
void sconv2d_spike_kernel(const float* __restrict__ x,
                          const float* __restrict__ wgt,
                          const float* __restrict__ thresh,
                          float* __restrict__ out)
{
    __shared__ float4   xs[NGMAX * NSITE];    // 49.4 KB
    __shared__ float    wds[KS * KS][CO];     // 1.2 KB
    __shared__ unsigned stg[256][5];          // 5.1 KB (stride 5: conflict-free)

    const int tid = threadIdx.x;
    for (int i = tid; i < KS * KS * CO; i += 256) {
        const int co  = i / (KS * KS);
        const int tap = i - co * (KS * KS);
        wds[tap][co] = wgt[co * (KS * KS) + tap];
    }
    const float th = thresh[0];

    // grid = 32 images x 16 tiles x 2 co-halves
    const int blk  = blockIdx.x;
    const int b    = blk >> 5;
    const int rest = blk & 31;
    const int tb   = rest >> 1;
    const int co0  = (rest & 1) * COB;
    const int h0   = (tb >> 2) << 4;
    const int w0   = (tb & 3) << 4;
    const int r    = tid >> 4;
    const int c    = tid & 15;

    const float* xb   = x   + (size_t)b * (HH * WW * TT);
    float*       outb = out + (size_t)b * (CO * HH * WW * TT);

    float ut[COB], sprev[COB];
    unsigned bw[COB * 4];
#pragma unroll
    for (int j = 0; j < COB; ++j) { ut[j] = 0.f; sprev[j] = 0.f; }
#pragma unroll
    for (int i = 0; i < COB * 4; ++i) bw[i] = 0u;

    process_chunk< 0, 28>(xb, xs, wds, tid, r, c, h0, w0, co0, th, ut, sprev, bw);
    process_chunk<28, 28>(xb, xs, wds, tid, r, c, h0, w0, co0, th, ut, sprev, bw);
    process_chunk<56, 28>(xb, xs, wds, tid, r, c, h0, w0, co0, th, ut, sprev, bw);
    process_chunk<84, 16>(xb, xs, wds, tid, r, c, h0, w0, co0, th, ut, sprev, bw);

    // ---- flush: per-co bit expansion, full-line coalesced float4 stores ----
#pragma unroll
    for (int j = 0; j < COB; ++j) {
        const int co = co0 + j;
        stg[tid][0] = bw[j * 4 + 0];
        stg[tid][1] = bw[j * 4 + 1];
        stg[tid][2] = bw[j * 4 + 2];
        stg[tid][3] = bw[j * 4 + 3];
        __syncthreads();
#pragma unroll
        for (int k = 0; k < 25; ++k) {
            const int idx = tid + k * 256;        // 0..6399
            const int u   = idx / 25;             // site 0..255
            const int tt  = (idx - u * 25) * 4;   // t0 of this float4 (4-aligned)
            const unsigned bs = stg[u][tt >> 5] >> (tt & 31);
            float4 v;
            v.x = (float)( bs        & 1u);
            v.y = (float)((bs >> 1)  & 1u);
            v.z = (float)((bs >> 2)  & 1u);
            v.w = (float)((bs >> 3)  & 1u);
            const int rr = u >> 4, cc = u & 15;
            *(float4*)(outb + (((size_t)co * HH + (h0 + rr)) * WW + (w0 + cc)) * TT + tt) = v;
        }
        __syncthreads();
    }
}

extern "C" void kernel_launch(void* const* d_in, const int* in_sizes, int n_in,
                              void* d_out, int out_size, void* d_ws, size_t ws_size,
                              hipStream_t stream) {
    const float* x      = (const float*)d_in[0];
    const float* wgt    = (const float*)d_in[1];
    const float* thresh = (const float*)d_in[2];
    float* out = (float*)d_out;

    dim3 grid(32 * 16 * 2);   // images x tiles x co-halves = 1024
    dim3 block(256);
    sconv2d_spike_kernel<<<grid, block, 0, stream>>>(x, wgt, thresh, out);
}